// Round 1
// baseline (758.802 us; speedup 1.0000x reference)
//
#include <hip/hip_runtime.h>
#include <math.h>

#define NUM_GRAPHS 512
#define D 128
#define NEG 0.01f
#define BN 32          // nodes per block in MLP kernel
#define XS_LD 260      // padded LDS row stride (floats), 16B-aligned rows

// ---------------------------------------------------------------------------
// Kernel 1: per-graph segment max + mean for one tensor.
// grid = (NUM_GRAPHS, 2)  [y: 0=topo, 1=geom], block = 256.
// batch is sorted, so graph g occupies a contiguous range found by binary search.
// pooled layout: pooled[g*512 + t*256 + {0..127: max, 128..255: mean}]
//   => combined-k mapping: k in [0,256) -> W1 row 128+k (t_max,t_mean)
//                          k in [256,512) -> W1 row 256+k (g_max,g_mean)
// ---------------------------------------------------------------------------
__global__ __launch_bounds__(256) void pool_kernel(
    const float* __restrict__ h_topo, const float* __restrict__ h_geom,
    const int* __restrict__ batch, int N, float* __restrict__ pooled)
{
    const int g = blockIdx.x;
    const int t = blockIdx.y;
    const float* __restrict__ h = t ? h_geom : h_topo;

    // lower_bound(batch, g) and lower_bound(batch, g+1)
    int lo = 0, hi = N;
    while (lo < hi) { int mid = (lo + hi) >> 1; if (batch[mid] < g) lo = mid + 1; else hi = mid; }
    const int start = lo;
    hi = N;
    while (lo < hi) { int mid = (lo + hi) >> 1; if (batch[mid] < g + 1) lo = mid + 1; else hi = mid; }
    const int end = lo;

    const int dim = threadIdx.x & 127;
    const int r   = threadIdx.x >> 7;   // 0 or 1: two rows in flight

    float mx = -INFINITY, sm = 0.0f;
    for (int row = start + r; row < end; row += 2) {
        float v = h[(size_t)row * D + dim];
        mx = fmaxf(mx, v);
        sm += v;
    }

    __shared__ float smx[256], ssm[256];
    smx[threadIdx.x] = mx;
    ssm[threadIdx.x] = sm;
    __syncthreads();

    if (threadIdx.x < 128) {
        mx = fmaxf(smx[threadIdx.x], smx[threadIdx.x + 128]);
        sm = ssm[threadIdx.x] + ssm[threadIdx.x + 128];
        float cnt  = (float)(end - start);
        float mean = sm / fmaxf(cnt, 1.0f);
        if (end <= start) { mx = 0.0f; mean = 0.0f; }  // empty graph: never gathered
        float* dst = pooled + (size_t)g * 512 + t * 256;
        dst[dim]       = mx;
        dst[128 + dim] = mean;
    }
}

// ---------------------------------------------------------------------------
// Kernel 2: per-graph bias P[g][j] = b1[j] + pooled[g] . W1[pooled rows][j]
// grid = NUM_GRAPHS, block = 256 (one thread per output column j).
// ---------------------------------------------------------------------------
__global__ __launch_bounds__(256) void pmat_kernel(
    const float* __restrict__ pooled, const float* __restrict__ W1,
    const float* __restrict__ b1, float* __restrict__ P)
{
    const int g = blockIdx.x;
    const int j = threadIdx.x;

    __shared__ float pl[512];
    pl[j]       = pooled[(size_t)g * 512 + j];
    pl[j + 256] = pooled[(size_t)g * 512 + 256 + j];
    __syncthreads();

    float acc = b1[j];
    #pragma unroll 8
    for (int k = 0; k < 256; ++k)          // t_max, t_mean -> W1 rows 128..383
        acc += pl[k] * W1[(size_t)(128 + k) * 256 + j];
    #pragma unroll 8
    for (int k = 0; k < 256; ++k)          // g_max, g_mean -> W1 rows 512..767
        acc += pl[256 + k] * W1[(size_t)(512 + k) * 256 + j];

    P[(size_t)g * 256 + j] = acc;
}

// ---------------------------------------------------------------------------
// Kernel 3: fused per-node MLP.
//   x = [h_topo[i], h_geom[i]] (256)
//   h = LeakyReLU( x @ W1'[256x256] + P[batch[i]] )   (W1' = rows 0:128 & 384:512)
//   out = h @ W2[256x128] + b2
// block = 256 threads, BN=32 nodes. Thread (tr=tid>>5, tc=tid&31):
//   nodes {tr, tr+8, tr+16, tr+24}; GEMM1 cols {4tc..4tc+3, 128+4tc..}; GEMM2 cols {4tc..}.
// One LDS buffer holds X then (after sync) H.
// ---------------------------------------------------------------------------
__global__ __launch_bounds__(256) void mlp_kernel(
    const float* __restrict__ h_topo, const float* __restrict__ h_geom,
    const int* __restrict__ batch, const float* __restrict__ P,
    const float* __restrict__ W1, const float* __restrict__ W2,
    const float* __restrict__ b2, float* __restrict__ out, int N)
{
    __shared__ float xs[BN][XS_LD];

    const int tid  = threadIdx.x;
    const int base = blockIdx.x * BN;

    // ---- stage X tile: xs[n][0:128]=topo, xs[n][128:256]=geom ----
    {
        const int n    = tid >> 3;              // 0..31
        const int q    = tid & 7;               // 0..7
        const int node = min(base + n, N - 1);
        const float4* tp = (const float4*)(h_topo + (size_t)node * D);
        const float4* gp = (const float4*)(h_geom + (size_t)node * D);
        #pragma unroll
        for (int i = 0; i < 4; ++i) {
            int k4 = q + i * 8;                 // 32 float4 slots per 128 floats
            *(float4*)&xs[n][k4 * 4]        = tp[k4];
            *(float4*)&xs[n][128 + k4 * 4]  = gp[k4];
        }
    }
    __syncthreads();

    const int tc = tid & 31, tr = tid >> 5;
    const int j0 = tc * 4;

    // ---- init accumulators from per-graph P ----
    float acc[4][8];
    #pragma unroll
    for (int nn = 0; nn < 4; ++nn) {
        const int node = min(base + tr + nn * 8, N - 1);
        const int g = batch[node];
        const float* Pr = P + (size_t)g * 256;
        float4 a = *(const float4*)&Pr[j0];
        float4 b = *(const float4*)&Pr[128 + j0];
        acc[nn][0] = a.x; acc[nn][1] = a.y; acc[nn][2] = a.z; acc[nn][3] = a.w;
        acc[nn][4] = b.x; acc[nn][5] = b.y; acc[nn][6] = b.z; acc[nn][7] = b.w;
    }

    // ---- GEMM1 part 1: topo rows (W1 rows 0..127) ----
    #pragma unroll 2
    for (int k = 0; k < 128; ++k) {
        const float* wr = W1 + (size_t)k * 256;
        float4 wa = *(const float4*)&wr[j0];
        float4 wb = *(const float4*)&wr[128 + j0];
        #pragma unroll
        for (int nn = 0; nn < 4; ++nn) {
            float x = xs[tr + nn * 8][k];
            acc[nn][0] += x * wa.x; acc[nn][1] += x * wa.y;
            acc[nn][2] += x * wa.z; acc[nn][3] += x * wa.w;
            acc[nn][4] += x * wb.x; acc[nn][5] += x * wb.y;
            acc[nn][6] += x * wb.z; acc[nn][7] += x * wb.w;
        }
    }
    // ---- GEMM1 part 2: geom rows (W1 rows 384..511) ----
    #pragma unroll 2
    for (int k = 0; k < 128; ++k) {
        const float* wr = W1 + (size_t)(384 + k) * 256;
        float4 wa = *(const float4*)&wr[j0];
        float4 wb = *(const float4*)&wr[128 + j0];
        #pragma unroll
        for (int nn = 0; nn < 4; ++nn) {
            float x = xs[tr + nn * 8][128 + k];
            acc[nn][0] += x * wa.x; acc[nn][1] += x * wa.y;
            acc[nn][2] += x * wa.z; acc[nn][3] += x * wa.w;
            acc[nn][4] += x * wb.x; acc[nn][5] += x * wb.y;
            acc[nn][6] += x * wb.z; acc[nn][7] += x * wb.w;
        }
    }

    __syncthreads();   // everyone done reading X

    // ---- LeakyReLU, write H into the same LDS buffer ----
    #pragma unroll
    for (int nn = 0; nn < 4; ++nn) {
        const int n = tr + nn * 8;
        #pragma unroll
        for (int jj = 0; jj < 8; ++jj) {
            float v = acc[nn][jj];
            v = (v >= 0.0f) ? v : NEG * v;
            int j = (jj < 4) ? (j0 + jj) : (128 + j0 + (jj - 4));
            xs[n][j] = v;
        }
    }
    __syncthreads();

    // ---- GEMM2: out = H @ W2 + b2 ----
    float acc2[4][4];
    {
        float4 bb = *(const float4*)&b2[j0];
        #pragma unroll
        for (int nn = 0; nn < 4; ++nn) {
            acc2[nn][0] = bb.x; acc2[nn][1] = bb.y;
            acc2[nn][2] = bb.z; acc2[nn][3] = bb.w;
        }
    }
    #pragma unroll 2
    for (int k = 0; k < 256; ++k) {
        float4 w = *(const float4*)&W2[(size_t)k * 128 + j0];
        #pragma unroll
        for (int nn = 0; nn < 4; ++nn) {
            float hv = xs[tr + nn * 8][k];
            acc2[nn][0] += hv * w.x; acc2[nn][1] += hv * w.y;
            acc2[nn][2] += hv * w.z; acc2[nn][3] += hv * w.w;
        }
    }

    // ---- store ----
    #pragma unroll
    for (int nn = 0; nn < 4; ++nn) {
        const int node = base + tr + nn * 8;
        if (node < N) {
            float4 o; o.x = acc2[nn][0]; o.y = acc2[nn][1];
                      o.z = acc2[nn][2]; o.w = acc2[nn][3];
            *(float4*)&out[(size_t)node * 128 + j0] = o;
        }
    }
}

// ---------------------------------------------------------------------------
extern "C" void kernel_launch(void* const* d_in, const int* in_sizes, int n_in,
                              void* d_out, int out_size, void* d_ws, size_t ws_size,
                              hipStream_t stream)
{
    const float* h_topo = (const float*)d_in[0];
    const float* h_geom = (const float*)d_in[1];
    const int*   batch  = (const int*)  d_in[2];
    const float* W1     = (const float*)d_in[3];
    const float* b1     = (const float*)d_in[4];
    const float* W2     = (const float*)d_in[5];
    const float* b2     = (const float*)d_in[6];
    float* out = (float*)d_out;

    const int N = in_sizes[0] / D;   // 200000

    float* pooled = (float*)d_ws;                       // 512*512 f32 = 1 MB
    float* P      = pooled + (size_t)NUM_GRAPHS * 512;  // 512*256 f32 = 512 KB

    pool_kernel<<<dim3(NUM_GRAPHS, 2), 256, 0, stream>>>(h_topo, h_geom, batch, N, pooled);
    pmat_kernel<<<NUM_GRAPHS, 256, 0, stream>>>(pooled, W1, b1, P);
    mlp_kernel<<<(N + BN - 1) / BN, 256, 0, stream>>>(h_topo, h_geom, batch, P,
                                                      W1, W2, b2, out, N);
}

// Round 2
// 214.792 us; speedup vs baseline: 3.5327x; 3.5327x over previous
//
#include <hip/hip_runtime.h>
#include <math.h>

#define NUM_GRAPHS 512
#define D 128
#define NEG 0.01f
#define BN 64   // nodes per block in MFMA MLP kernel

typedef __attribute__((ext_vector_type(8))) short  bf16x8;  // MFMA A/B frag (8 bf16)
typedef __attribute__((ext_vector_type(4))) float  f32x4;   // MFMA C/D frag
typedef __attribute__((ext_vector_type(8))) unsigned short u16x8;

__device__ __forceinline__ unsigned short f2bf(float f) {
    unsigned u = __float_as_uint(f);
    u += 0x7fffu + ((u >> 16) & 1u);   // round-to-nearest-even
    return (unsigned short)(u >> 16);
}

// ---------------------------------------------------------------------------
// Kernel 1: per-graph segment max + mean, float4-vectorized, 8 rows in flight.
// grid = (NUM_GRAPHS, 2) [y: 0=topo, 1=geom], block = 256.
// pooled[g*512 + t*256 + {0..127:max, 128..255:mean}]
// ---------------------------------------------------------------------------
__global__ __launch_bounds__(256) void pool_kernel(
    const float* __restrict__ h_topo, const float* __restrict__ h_geom,
    const int* __restrict__ batch, int N, float* __restrict__ pooled)
{
    const int g = blockIdx.x, t = blockIdx.y;
    const float* __restrict__ h = t ? h_geom : h_topo;

    int lo = 0, hi = N;
    while (lo < hi) { int m = (lo + hi) >> 1; if (batch[m] < g) lo = m + 1; else hi = m; }
    const int start = lo; hi = N;
    while (lo < hi) { int m = (lo + hi) >> 1; if (batch[m] < g + 1) lo = m + 1; else hi = m; }
    const int end = lo;

    const int c = threadIdx.x & 31;   // float4 column
    const int r = threadIdx.x >> 5;   // 0..7 row phase

    float4 mx = make_float4(-INFINITY, -INFINITY, -INFINITY, -INFINITY);
    float4 sm = make_float4(0.f, 0.f, 0.f, 0.f);
    for (int row = start + r; row < end; row += 8) {
        float4 v = *(const float4*)(h + (size_t)row * D + c * 4);
        mx.x = fmaxf(mx.x, v.x); mx.y = fmaxf(mx.y, v.y);
        mx.z = fmaxf(mx.z, v.z); mx.w = fmaxf(mx.w, v.w);
        sm.x += v.x; sm.y += v.y; sm.z += v.z; sm.w += v.w;
    }

    __shared__ float4 smx[256], ssm[256];
    smx[threadIdx.x] = mx; ssm[threadIdx.x] = sm;
    __syncthreads();
    #pragma unroll
    for (int s = 4; s > 0; s >>= 1) {
        if (r < s) {
            float4 a = smx[threadIdx.x + s * 32];
            float4 b = ssm[threadIdx.x + s * 32];
            float4 m0 = smx[threadIdx.x];
            float4 s0 = ssm[threadIdx.x];
            m0.x = fmaxf(m0.x, a.x); m0.y = fmaxf(m0.y, a.y);
            m0.z = fmaxf(m0.z, a.z); m0.w = fmaxf(m0.w, a.w);
            s0.x += b.x; s0.y += b.y; s0.z += b.z; s0.w += b.w;
            smx[threadIdx.x] = m0; ssm[threadIdx.x] = s0;
        }
        __syncthreads();
    }
    if (r == 0) {
        float4 m0 = smx[threadIdx.x], s0 = ssm[threadIdx.x];
        const float cnt = (float)(end - start);
        const float inv = 1.0f / fmaxf(cnt, 1.0f);
        float4 mean = make_float4(s0.x * inv, s0.y * inv, s0.z * inv, s0.w * inv);
        if (end <= start) { m0 = make_float4(0,0,0,0); mean = make_float4(0,0,0,0); }
        float* dst = pooled + (size_t)g * 512 + t * 256;
        *(float4*)(dst + c * 4)       = m0;
        *(float4*)(dst + 128 + c * 4) = mean;
    }
}

// ---------------------------------------------------------------------------
// Kernel 2: per-graph bias P[g][j] = b1[j] + pooled[g] . W1[pooled rows][j]
// (exact f32 — folds 512 of the 768 K-dims outside the bf16 path)
// ---------------------------------------------------------------------------
__global__ __launch_bounds__(256) void pmat_kernel(
    const float* __restrict__ pooled, const float* __restrict__ W1,
    const float* __restrict__ b1, float* __restrict__ P)
{
    const int g = blockIdx.x;
    const int j = threadIdx.x;

    __shared__ float pl[512];
    pl[j]       = pooled[(size_t)g * 512 + j];
    pl[j + 256] = pooled[(size_t)g * 512 + 256 + j];
    __syncthreads();

    float acc = b1[j];
    #pragma unroll 8
    for (int k = 0; k < 256; ++k)          // t_max,t_mean -> W1 rows 128..383
        acc += pl[k] * W1[(size_t)(128 + k) * 256 + j];
    #pragma unroll 8
    for (int k = 0; k < 256; ++k)          // g_max,g_mean -> W1 rows 512..767
        acc += pl[256 + k] * W1[(size_t)(512 + k) * 256 + j];

    P[(size_t)g * 256 + j] = acc;
}

// ---------------------------------------------------------------------------
// Kernel 3: weight pre-convert to transposed bf16.
// W1bT[n][k] = bf16(W1[kmap(k)][n]), kmap(k) = k<128 ? k : k+256 (topo/geom rows)
// W2bT[n][k] = bf16(W2[k][n])
// ---------------------------------------------------------------------------
__global__ __launch_bounds__(256) void wconv_kernel(
    const float* __restrict__ W1, const float* __restrict__ W2,
    unsigned short* __restrict__ W1bT, unsigned short* __restrict__ W2bT)
{
    const int idx = blockIdx.x * 256 + threadIdx.x;
    if (idx < 256 * 256) {
        const int n = idx >> 8, k = idx & 255;
        const int kk = (k < 128) ? k : (k + 256);
        W1bT[idx] = f2bf(W1[(size_t)kk * 256 + n]);
    } else {
        const int j = idx - 256 * 256;
        if (j < 128 * 256) {
            const int n = j >> 8, k = j & 255;
            W2bT[j] = f2bf(W2[(size_t)k * 128 + n]);
        }
    }
}

// ---------------------------------------------------------------------------
// Kernel 4: fused MFMA MLP. 64 nodes/block, 4 waves.
// GEMM1: C1[64,256] = Xb[64,256] @ W1'b + P[batch]  (wave w owns cols w*64..)
// H = LeakyReLU(C1) -> bf16, overwrites X in LDS
// GEMM2: out[64,128] = H @ W2b + b2                 (wave w owns cols w*32..)
// LDS X/H layout: [row][k] bf16, ushort idx ^= (row&7)<<3 (bank swizzle).
// MFMA 16x16x32 bf16 frags: A: row=l&15, k=(l>>4)*8+j ; B: col=l&15, same k;
// D: col=l&15, row=(l>>4)*4+q (m89-verified).
// ---------------------------------------------------------------------------
__global__ __launch_bounds__(256) void mlp_mfma(
    const float* __restrict__ h_topo, const float* __restrict__ h_geom,
    const int* __restrict__ batch, const float* __restrict__ P,
    const unsigned short* __restrict__ W1bT, const unsigned short* __restrict__ W2bT,
    const float* __restrict__ b2, float* __restrict__ out, int N)
{
    __shared__ unsigned short xs[64 * 256];   // 32 KB, X then H
    __shared__ int gid[64];

    const int tid  = threadIdx.x;
    const int wave = tid >> 6, lane = tid & 63;
    const int base = blockIdx.x * BN;

    // ---- stage X tile as bf16 (swizzled) ----
    {
        const int row  = tid >> 2;           // 0..63
        const int kq   = tid & 3;            // 0..3 (64-float chunk)
        const int node = min(base + row, N - 1);
        const float* src = (kq < 2) ? (h_topo + (size_t)node * D + kq * 64)
                                    : (h_geom + (size_t)node * D + (kq - 2) * 64);
        #pragma unroll
        for (int i = 0; i < 8; ++i) {
            float4 a = ((const float4*)src)[2 * i];
            float4 b = ((const float4*)src)[2 * i + 1];
            u16x8 v;
            v[0] = f2bf(a.x); v[1] = f2bf(a.y); v[2] = f2bf(a.z); v[3] = f2bf(a.w);
            v[4] = f2bf(b.x); v[5] = f2bf(b.y); v[6] = f2bf(b.z); v[7] = f2bf(b.w);
            const int k   = kq * 64 + i * 8;
            const int idx = (row * 256 + k) ^ ((row & 7) << 3);
            *(u16x8*)&xs[idx] = v;
        }
        if (tid < 64) gid[tid] = batch[min(base + tid, N - 1)];
    }
    __syncthreads();

    const int lhi = lane >> 4;   // 0..3
    const int llo = lane & 15;   // 0..15

    // ---- GEMM1 ----
    f32x4 acc[4][4];
    #pragma unroll
    for (int i = 0; i < 4; ++i)
        #pragma unroll
        for (int j = 0; j < 4; ++j)
            acc[i][j] = (f32x4){0.f, 0.f, 0.f, 0.f};

    #pragma unroll
    for (int ks = 0; ks < 8; ++ks) {
        const int kb = ks * 32 + lhi * 8;
        bf16x8 afr[4], bfr[4];
        #pragma unroll
        for (int rt = 0; rt < 4; ++rt) {
            const int ar = rt * 16 + llo;
            afr[rt] = *(const bf16x8*)&xs[(ar * 256 + kb) ^ ((ar & 7) << 3)];
        }
        #pragma unroll
        for (int ct = 0; ct < 4; ++ct) {
            const int col = wave * 64 + ct * 16 + llo;
            bfr[ct] = *(const bf16x8*)(W1bT + (size_t)col * 256 + kb);
        }
        #pragma unroll
        for (int rt = 0; rt < 4; ++rt)
            #pragma unroll
            for (int ct = 0; ct < 4; ++ct)
                acc[rt][ct] = __builtin_amdgcn_mfma_f32_16x16x32_bf16(
                    afr[rt], bfr[ct], acc[rt][ct], 0, 0, 0);
    }
    __syncthreads();   // all waves done reading X

    // ---- epilogue 1: +P[batch], LeakyReLU, write H (bf16) over X ----
    #pragma unroll
    for (int rt = 0; rt < 4; ++rt) {
        #pragma unroll
        for (int ct = 0; ct < 4; ++ct) {
            const int col = wave * 64 + ct * 16 + llo;
            #pragma unroll
            for (int q = 0; q < 4; ++q) {
                const int row = rt * 16 + lhi * 4 + q;
                float v = acc[rt][ct][q] + P[(size_t)gid[row] * 256 + col];
                v = (v >= 0.f) ? v : NEG * v;
                xs[(row * 256 + col) ^ ((row & 7) << 3)] = f2bf(v);
            }
        }
    }
    __syncthreads();

    // ---- GEMM2 ----
    f32x4 acc2[4][2];
    #pragma unroll
    for (int ct = 0; ct < 2; ++ct) {
        const float bv = b2[wave * 32 + ct * 16 + llo];
        #pragma unroll
        for (int rt = 0; rt < 4; ++rt)
            acc2[rt][ct] = (f32x4){bv, bv, bv, bv};
    }
    #pragma unroll
    for (int ks = 0; ks < 8; ++ks) {
        const int kb = ks * 32 + lhi * 8;
        bf16x8 afr[4], bfr[2];
        #pragma unroll
        for (int rt = 0; rt < 4; ++rt) {
            const int ar = rt * 16 + llo;
            afr[rt] = *(const bf16x8*)&xs[(ar * 256 + kb) ^ ((ar & 7) << 3)];
        }
        #pragma unroll
        for (int ct = 0; ct < 2; ++ct) {
            const int col = wave * 32 + ct * 16 + llo;
            bfr[ct] = *(const bf16x8*)(W2bT + (size_t)col * 256 + kb);
        }
        #pragma unroll
        for (int rt = 0; rt < 4; ++rt)
            #pragma unroll
            for (int ct = 0; ct < 2; ++ct)
                acc2[rt][ct] = __builtin_amdgcn_mfma_f32_16x16x32_bf16(
                    afr[rt], bfr[ct], acc2[rt][ct], 0, 0, 0);
    }

    // ---- store out (f32) ----
    #pragma unroll
    for (int rt = 0; rt < 4; ++rt) {
        #pragma unroll
        for (int ct = 0; ct < 2; ++ct) {
            #pragma unroll
            for (int q = 0; q < 4; ++q) {
                const int row  = rt * 16 + lhi * 4 + q;
                const int node = base + row;
                if (node < N)
                    out[(size_t)node * 128 + wave * 32 + ct * 16 + llo] = acc2[rt][ct][q];
            }
        }
    }
}

// ---------------------------------------------------------------------------
extern "C" void kernel_launch(void* const* d_in, const int* in_sizes, int n_in,
                              void* d_out, int out_size, void* d_ws, size_t ws_size,
                              hipStream_t stream)
{
    const float* h_topo = (const float*)d_in[0];
    const float* h_geom = (const float*)d_in[1];
    const int*   batch  = (const int*)  d_in[2];
    const float* W1     = (const float*)d_in[3];
    const float* b1     = (const float*)d_in[4];
    const float* W2     = (const float*)d_in[5];
    const float* b2     = (const float*)d_in[6];
    float* out = (float*)d_out;

    const int N = in_sizes[0] / D;   // 200000

    float*          pooled = (float*)d_ws;                         // 512*512 f32
    float*          P      = pooled + (size_t)NUM_GRAPHS * 512;    // 512*256 f32
    unsigned short* W1bT   = (unsigned short*)(P + (size_t)NUM_GRAPHS * 256); // 256*256 bf16
    unsigned short* W2bT   = W1bT + 256 * 256;                     // 128*256 bf16

    wconv_kernel<<<(256 * 256 + 128 * 256) / 256, 256, 0, stream>>>(W1, W2, W1bT, W2bT);
    pool_kernel<<<dim3(NUM_GRAPHS, 2), 256, 0, stream>>>(h_topo, h_geom, batch, N, pooled);
    pmat_kernel<<<NUM_GRAPHS, 256, 0, stream>>>(pooled, W1, b1, P);
    mlp_mfma<<<(N + BN - 1) / BN, 256, 0, stream>>>(h_topo, h_geom, batch, P,
                                                    W1bT, W2bT, b2, out, N);
}